// Round 1
// baseline (127.738 us; speedup 1.0000x reference)
//
#include <hip/hip_runtime.h>

#define BLOCK 256
#define P     8      // self points per thread
#define SPLIT 8      // splits of the "other" axis
#define CHUNK 512    // other points staged per block = NPTS/SPLIT
#define NPTS  4096
#define BATCH 16

__global__ __launch_bounds__(BLOCK) void chamfer_min_kernel(
    const float* __restrict__ p1, const float* __restrict__ p2,
    unsigned int* __restrict__ minbuf)
{
    __shared__ float4 sm[CHUNK];
    const int tid = threadIdx.x;
    const int s   = blockIdx.x & (SPLIT - 1);   // split over other points
    const int j   = blockIdx.x >> 3;            // self-point block (0..1)
    const int b   = blockIdx.y;
    const int dir = blockIdx.z;

    const float* selfp  = (dir == 0 ? p1 : p2) + (size_t)b * NPTS * 3;
    const float* otherp = (dir == 0 ? p2 : p1) + (size_t)b * NPTS * 3;

    // Stage CHUNK other points, transformed to (-2x, -2y, -2z, |p|^2).
    // 128 threads x 4 points each; 12 contiguous floats = 3 float4 per thread.
    if (tid < CHUNK / 4) {
        const float4* src = (const float4*)(otherp + (size_t)s * CHUNK * 3);
        float4 a = src[tid * 3 + 0];
        float4 c = src[tid * 3 + 1];
        float4 e = src[tid * 3 + 2];
        float px[4][3] = {{a.x, a.y, a.z}, {a.w, c.x, c.y},
                          {c.z, c.w, e.x}, {e.y, e.z, e.w}};
#pragma unroll
        for (int k = 0; k < 4; ++k) {
            float sx = px[k][0], sy = px[k][1], sz = px[k][2];
            sm[tid * 4 + k] = make_float4(-2.f * sx, -2.f * sy, -2.f * sz,
                                          sx * sx + sy * sy + sz * sz);
        }
    }

    // Load this thread's 8 self points (24 contiguous floats = 6 float4).
    float x[P][3];
    {
        const float4* src = (const float4*)(selfp + (size_t)j * (BLOCK * P) * 3);
        float4 v[6];
#pragma unroll
        for (int k = 0; k < 6; ++k) v[k] = src[tid * 6 + k];
        const float* f = (const float*)v;
#pragma unroll
        for (int p = 0; p < P; ++p) {
            x[p][0] = f[p * 3 + 0];
            x[p][1] = f[p * 3 + 1];
            x[p][2] = f[p * 3 + 2];
        }
    }
    __syncthreads();

    float m[P];
#pragma unroll
    for (int p = 0; p < P; ++p) m[p] = 3.4e38f;

#pragma unroll 2
    for (int u = 0; u < CHUNK; ++u) {
        float4 zz = sm[u];
#pragma unroll
        for (int p = 0; p < P; ++p) {
            float t = fmaf(x[p][0], zz.x,
                      fmaf(x[p][1], zz.y,
                      fmaf(x[p][2], zz.z, zz.w)));
            m[p] = fminf(m[p], t);
        }
    }

    unsigned int* dst =
        minbuf + ((size_t)dir * BATCH + b) * NPTS + (size_t)j * (BLOCK * P) + (size_t)tid * P;
#pragma unroll
    for (int p = 0; p < P; ++p) {
        float sq = fmaf(x[p][0], x[p][0],
                   fmaf(x[p][1], x[p][1], x[p][2] * x[p][2]));
        float d = fmaxf(sq + m[p], 0.0f);   // clamp keeps uint-min ordering valid
        atomicMin(dst + p, __float_as_uint(d));
    }
}

__global__ __launch_bounds__(256) void chamfer_reduce_kernel(
    const unsigned int* __restrict__ minbuf, float* __restrict__ out,
    int n, float scale)
{
    float s = 0.f;
    for (int i = blockIdx.x * blockDim.x + threadIdx.x; i < n;
         i += gridDim.x * blockDim.x)
        s += __uint_as_float(minbuf[i]);
#pragma unroll
    for (int off = 32; off > 0; off >>= 1)
        s += __shfl_down(s, off, 64);
    __shared__ float ws4[4];
    int lane = threadIdx.x & 63, wv = threadIdx.x >> 6;
    if (lane == 0) ws4[wv] = s;
    __syncthreads();
    if (threadIdx.x == 0) {
        float t = ws4[0] + ws4[1] + ws4[2] + ws4[3];
        atomicAdd(out, t * scale);
    }
}

extern "C" void kernel_launch(void* const* d_in, const int* in_sizes, int n_in,
                              void* d_out, int out_size, void* d_ws, size_t ws_size,
                              hipStream_t stream) {
    const float* p1 = (const float*)d_in[0];
    const float* p2 = (const float*)d_in[1];
    float* out = (float*)d_out;
    unsigned int* minbuf = (unsigned int*)d_ws;
    const size_t nmin = (size_t)2 * BATCH * NPTS;

    hipMemsetAsync(out, 0, sizeof(float), stream);
    hipMemsetAsync(minbuf, 0xFF, nmin * sizeof(unsigned int), stream);

    dim3 grid(2 * SPLIT, BATCH, 2);   // 16 x 16 x 2 = 512 blocks
    chamfer_min_kernel<<<grid, BLOCK, 0, stream>>>(p1, p2, minbuf);
    chamfer_reduce_kernel<<<128, 256, 0, stream>>>(minbuf, out, (int)nmin,
                                                   1.0f / BATCH);
}

// Round 2
// 106.338 us; speedup vs baseline: 1.2012x; 1.2012x over previous
//
#include <hip/hip_runtime.h>

#define BLOCK 256
#define P     4                  // self points per thread
#define SPLIT 8                  // splits of the "other" axis
#define CHUNK 512                // other points staged per block = NPTS/SPLIT
#define NPTS  4096
#define BATCH 16
#define NMIN  ((size_t)2 * BATCH * NPTS)   // 131072 min-slots

// per_split != 0: minbuf has SPLIT planes of NMIN floats, plain stores.
// per_split == 0: minbuf is NMIN uints pre-set to 0xFF, atomicMin on bits.
__global__ __launch_bounds__(BLOCK) void chamfer_min_kernel(
    const float* __restrict__ p1, const float* __restrict__ p2,
    unsigned int* __restrict__ minbuf, int per_split)
{
    __shared__ float4 sm[CHUNK];
    const int tid = threadIdx.x;
    const int s   = blockIdx.x & (SPLIT - 1);
    const int j   = blockIdx.x >> 3;            // self chunk 0..3 (1024 pts each)
    const int b   = blockIdx.y;
    const int dir = blockIdx.z;

    const float* selfp  = (dir == 0 ? p1 : p2) + (size_t)b * NPTS * 3;
    const float* otherp = (dir == 0 ? p2 : p1) + (size_t)b * NPTS * 3;

    // Stage CHUNK=512 other points as (-2x,-2y,-2z,|p|^2): 128 threads x 4 pts.
    if (tid < CHUNK / 4) {
        const float4* src = (const float4*)(otherp + (size_t)s * CHUNK * 3);
        float4 a = src[tid * 3 + 0];
        float4 c = src[tid * 3 + 1];
        float4 e = src[tid * 3 + 2];
        float px[4][3] = {{a.x, a.y, a.z}, {a.w, c.x, c.y},
                          {c.z, c.w, e.x}, {e.y, e.z, e.w}};
#pragma unroll
        for (int k = 0; k < 4; ++k) {
            float sx = px[k][0], sy = px[k][1], sz = px[k][2];
            sm[tid * 4 + k] = make_float4(-2.f * sx, -2.f * sy, -2.f * sz,
                                          sx * sx + sy * sy + sz * sz);
        }
    }

    // Load this thread's 4 self points (12 contiguous floats = 3 float4).
    float x[P][3];
    {
        const float4* src = (const float4*)(selfp + (size_t)j * (BLOCK * P) * 3);
        float4 v0 = src[tid * 3 + 0];
        float4 v1 = src[tid * 3 + 1];
        float4 v2 = src[tid * 3 + 2];
        float f[12] = {v0.x, v0.y, v0.z, v0.w, v1.x, v1.y, v1.z, v1.w,
                       v2.x, v2.y, v2.z, v2.w};
#pragma unroll
        for (int p = 0; p < P; ++p) {
            x[p][0] = f[p * 3 + 0];
            x[p][1] = f[p * 3 + 1];
            x[p][2] = f[p * 3 + 2];
        }
    }
    __syncthreads();

    float m[P];
#pragma unroll
    for (int p = 0; p < P; ++p) m[p] = 3.4e38f;

#pragma unroll 4
    for (int u = 0; u < CHUNK; u += 2) {
        float4 za = sm[u];
        float4 zb = sm[u + 1];
#pragma unroll
        for (int p = 0; p < P; ++p) {
            float t0 = fmaf(x[p][0], za.x,
                       fmaf(x[p][1], za.y,
                       fmaf(x[p][2], za.z, za.w)));
            float t1 = fmaf(x[p][0], zb.x,
                       fmaf(x[p][1], zb.y,
                       fmaf(x[p][2], zb.z, zb.w)));
            m[p] = fminf(fminf(t0, t1), m[p]);   // -> v_min3_f32
        }
    }

    const size_t base =
        ((size_t)dir * BATCH + b) * NPTS + (size_t)j * (BLOCK * P) + (size_t)tid * P;
#pragma unroll
    for (int p = 0; p < P; ++p) {
        float sq = fmaf(x[p][0], x[p][0],
                   fmaf(x[p][1], x[p][1], x[p][2] * x[p][2]));
        float d = fmaxf(sq + m[p], 0.0f);        // >=0: uint order == float order
        if (per_split) {
            minbuf[(size_t)s * NMIN + base + p] = __float_as_uint(d);
        } else {
            atomicMin(minbuf + base + p, __float_as_uint(d));
        }
    }
}

// per-split path: min over SPLIT planes, sum, atomicAdd (out pre-zeroed).
__global__ __launch_bounds__(256) void chamfer_reduce_split(
    const float* __restrict__ minbuf, float* __restrict__ out, float scale)
{
    int i = blockIdx.x * 256 + threadIdx.x;     // grid covers NMIN exactly
    float mn = minbuf[i];
#pragma unroll
    for (int s = 1; s < SPLIT; ++s)
        mn = fminf(mn, minbuf[(size_t)s * NMIN + i]);
    float v = mn;
#pragma unroll
    for (int off = 32; off > 0; off >>= 1) v += __shfl_down(v, off, 64);
    __shared__ float ws4[4];
    int lane = threadIdx.x & 63, wv = threadIdx.x >> 6;
    if (lane == 0) ws4[wv] = v;
    __syncthreads();
    if (threadIdx.x == 0)
        atomicAdd(out, (ws4[0] + ws4[1] + ws4[2] + ws4[3]) * scale);
}

// atomic path: single block sums NMIN uint-bit floats, writes out directly.
__global__ __launch_bounds__(1024) void chamfer_reduce_atomicpath(
    const unsigned int* __restrict__ minbuf, float* __restrict__ out, float scale)
{
    float v = 0.f;
    for (size_t i = threadIdx.x; i < NMIN; i += 1024)
        v += __uint_as_float(minbuf[i]);
#pragma unroll
    for (int off = 32; off > 0; off >>= 1) v += __shfl_down(v, off, 64);
    __shared__ float ws16[16];
    int lane = threadIdx.x & 63, wv = threadIdx.x >> 6;
    if (lane == 0) ws16[wv] = v;
    __syncthreads();
    if (threadIdx.x == 0) {
        float t = 0.f;
#pragma unroll
        for (int k = 0; k < 16; ++k) t += ws16[k];
        out[0] = t * scale;
    }
}

extern "C" void kernel_launch(void* const* d_in, const int* in_sizes, int n_in,
                              void* d_out, int out_size, void* d_ws, size_t ws_size,
                              hipStream_t stream) {
    const float* p1 = (const float*)d_in[0];
    const float* p2 = (const float*)d_in[1];
    float* out = (float*)d_out;
    unsigned int* minbuf = (unsigned int*)d_ws;

    const size_t split_bytes = (size_t)SPLIT * NMIN * sizeof(unsigned int); // 4 MB
    const int per_split = (ws_size >= split_bytes) ? 1 : 0;

    dim3 grid(4 * SPLIT, BATCH, 2);   // 32 x 16 x 2 = 1024 blocks
    if (per_split) {
        hipMemsetAsync(out, 0, sizeof(float), stream);
        chamfer_min_kernel<<<grid, BLOCK, 0, stream>>>(p1, p2, minbuf, 1);
        chamfer_reduce_split<<<NMIN / 256, 256, 0, stream>>>(
            (const float*)minbuf, out, 1.0f / BATCH);
    } else {
        hipMemsetAsync(minbuf, 0xFF, NMIN * sizeof(unsigned int), stream);
        chamfer_min_kernel<<<grid, BLOCK, 0, stream>>>(p1, p2, minbuf, 0);
        chamfer_reduce_atomicpath<<<1, 1024, 0, stream>>>(minbuf, out, 1.0f / BATCH);
    }
}

// Round 3
// 103.936 us; speedup vs baseline: 1.2290x; 1.0231x over previous
//
#include <hip/hip_runtime.h>

#define BLOCK 256
#define WAVES 4
#define PSELF 16                 // self points per lane (each wave covers all 1024)
#define SELFS 1024               // self points per block
#define SPLIT 8                  // splits of the "other" axis across blocks
#define CHUNK 512                // others staged per block
#define WCH   128                // others per wave = CHUNK/WAVES
#define NPTS  4096
#define BATCH 16
#define NMIN  ((size_t)2 * BATCH * NPTS)
#define WPAD  (SELFS + SELFS / 16)   // +1 pad per 16 -> stride 17, no bank conflicts

__global__ __launch_bounds__(BLOCK, 4) void chamfer_min_kernel(
    const float* __restrict__ p1, const float* __restrict__ p2,
    unsigned int* __restrict__ minbuf, int per_split)
{
    __shared__ float4 sm[CHUNK];           // 8 KB: (-2x,-2y,-2z,|p|^2)
    __shared__ float wmin[WAVES][WPAD];    // ~17 KB: per-wave partial mins

    const int tid  = threadIdx.x;
    const int lane = tid & 63;
    const int wv   = tid >> 6;
    const int s    = blockIdx.x & (SPLIT - 1);
    const int j    = blockIdx.x >> 3;      // self chunk 0..3 (1024 pts each)
    const int b    = blockIdx.y;
    const int dir  = blockIdx.z;

    const float* selfp  = (dir == 0 ? p1 : p2) + (size_t)b * NPTS * 3;
    const float* otherp = (dir == 0 ? p2 : p1) + (size_t)b * NPTS * 3;

    // Stage CHUNK=512 others as (-2x,-2y,-2z,|p|^2): 128 threads x 4 pts.
    if (tid < CHUNK / 4) {
        const float4* src = (const float4*)(otherp + (size_t)s * CHUNK * 3);
        float4 a = src[tid * 3 + 0];
        float4 c = src[tid * 3 + 1];
        float4 e = src[tid * 3 + 2];
        float px[4][3] = {{a.x, a.y, a.z}, {a.w, c.x, c.y},
                          {c.z, c.w, e.x}, {e.y, e.z, e.w}};
#pragma unroll
        for (int k = 0; k < 4; ++k) {
            float sx = px[k][0], sy = px[k][1], sz = px[k][2];
            sm[tid * 4 + k] = make_float4(-2.f * sx, -2.f * sy, -2.f * sz,
                                          sx * sx + sy * sy + sz * sz);
        }
    }

    // Each lane owns self points lane*16..lane*16+15 (identical in all waves).
    // 16 pts = 48 floats = 12 float4, contiguous per lane.
    float x[PSELF][3];
    {
        const float4* src = (const float4*)(selfp + (size_t)j * SELFS * 3);
        float4 v[12];
#pragma unroll
        for (int k = 0; k < 12; ++k) v[k] = src[lane * 12 + k];
        const float* f = (const float*)v;
#pragma unroll
        for (int p = 0; p < PSELF; ++p) {
            x[p][0] = f[p * 3 + 0];
            x[p][1] = f[p * 3 + 1];
            x[p][2] = f[p * 3 + 2];
        }
    }
    __syncthreads();

    float m[PSELF];
#pragma unroll
    for (int p = 0; p < PSELF; ++p) m[p] = 3.4e38f;

    // Each wave streams only its 128-other sub-range: 4x less DS traffic.
    const int ob = wv * WCH;
#pragma unroll 2
    for (int u = 0; u < WCH; u += 2) {
        float4 za = sm[ob + u];
        float4 zb = sm[ob + u + 1];
#pragma unroll
        for (int p = 0; p < PSELF; ++p) {
            float t0 = fmaf(x[p][0], za.x,
                       fmaf(x[p][1], za.y,
                       fmaf(x[p][2], za.z, za.w)));
            float t1 = fmaf(x[p][0], zb.x,
                       fmaf(x[p][1], zb.y,
                       fmaf(x[p][2], zb.z, zb.w)));
            m[p] = fminf(fminf(t0, t1), m[p]);   // -> v_min3_f32
        }
    }

    // d = |x|^2 + partial_min, clamp >=0 so uint order == float order later.
#pragma unroll
    for (int p = 0; p < PSELF; ++p) {
        float sq = fmaf(x[p][0], x[p][0],
                   fmaf(x[p][1], x[p][1], x[p][2] * x[p][2]));
        float d = fmaxf(sq + m[p], 0.0f);
        int slot = lane * PSELF + p;           // slot>>4 == lane
        wmin[wv][slot + (slot >> 4)] = d;      // stride-17: conflict-free
    }
    __syncthreads();

    // Cross-wave combine: thread tid handles self slots tid*4..tid*4+3.
    const size_t base = ((size_t)dir * BATCH + b) * NPTS + (size_t)j * SELFS;
    float r[4];
#pragma unroll
    for (int i = 0; i < 4; ++i) {
        int slot = tid * 4 + i;
        int ps = slot + (slot >> 4);
        float mn = fminf(fminf(wmin[0][ps], wmin[1][ps]),
                         fminf(wmin[2][ps], wmin[3][ps]));
        r[i] = mn;
    }
    if (per_split) {
        float4* dst = (float4*)((float*)minbuf + (size_t)s * NMIN + base) + tid;
        *dst = make_float4(r[0], r[1], r[2], r[3]);
    } else {
#pragma unroll
        for (int i = 0; i < 4; ++i)
            atomicMin(minbuf + base + (size_t)tid * 4 + i, __float_as_uint(r[i]));
    }
}

// per-split path: min over SPLIT planes, sum, atomicAdd (out pre-zeroed).
__global__ __launch_bounds__(256) void chamfer_reduce_split(
    const float* __restrict__ minbuf, float* __restrict__ out, float scale)
{
    int i = blockIdx.x * 256 + threadIdx.x;     // grid covers NMIN exactly
    float mn = minbuf[i];
#pragma unroll
    for (int s = 1; s < SPLIT; ++s)
        mn = fminf(mn, minbuf[(size_t)s * NMIN + i]);
    float v = mn;
#pragma unroll
    for (int off = 32; off > 0; off >>= 1) v += __shfl_down(v, off, 64);
    __shared__ float ws4[4];
    int lane = threadIdx.x & 63, wv = threadIdx.x >> 6;
    if (lane == 0) ws4[wv] = v;
    __syncthreads();
    if (threadIdx.x == 0)
        atomicAdd(out, (ws4[0] + ws4[1] + ws4[2] + ws4[3]) * scale);
}

// atomic fallback: single block sums NMIN uint-bit floats, writes out directly.
__global__ __launch_bounds__(1024) void chamfer_reduce_atomicpath(
    const unsigned int* __restrict__ minbuf, float* __restrict__ out, float scale)
{
    float v = 0.f;
    for (size_t i = threadIdx.x; i < NMIN; i += 1024)
        v += __uint_as_float(minbuf[i]);
#pragma unroll
    for (int off = 32; off > 0; off >>= 1) v += __shfl_down(v, off, 64);
    __shared__ float ws16[16];
    int lane = threadIdx.x & 63, wv = threadIdx.x >> 6;
    if (lane == 0) ws16[wv] = v;
    __syncthreads();
    if (threadIdx.x == 0) {
        float t = 0.f;
#pragma unroll
        for (int k = 0; k < 16; ++k) t += ws16[k];
        out[0] = t * scale;
    }
}

extern "C" void kernel_launch(void* const* d_in, const int* in_sizes, int n_in,
                              void* d_out, int out_size, void* d_ws, size_t ws_size,
                              hipStream_t stream) {
    const float* p1 = (const float*)d_in[0];
    const float* p2 = (const float*)d_in[1];
    float* out = (float*)d_out;
    unsigned int* minbuf = (unsigned int*)d_ws;

    const size_t split_bytes = (size_t)SPLIT * NMIN * sizeof(unsigned int); // 4 MB
    const int per_split = (ws_size >= split_bytes) ? 1 : 0;

    dim3 grid(4 * SPLIT, BATCH, 2);   // 32 x 16 x 2 = 1024 blocks
    if (per_split) {
        hipMemsetAsync(out, 0, sizeof(float), stream);
        chamfer_min_kernel<<<grid, BLOCK, 0, stream>>>(p1, p2, minbuf, 1);
        chamfer_reduce_split<<<NMIN / 256, 256, 0, stream>>>(
            (const float*)minbuf, out, 1.0f / BATCH);
    } else {
        hipMemsetAsync(minbuf, 0xFF, NMIN * sizeof(unsigned int), stream);
        chamfer_min_kernel<<<grid, BLOCK, 0, stream>>>(p1, p2, minbuf, 0);
        chamfer_reduce_atomicpath<<<1, 1024, 0, stream>>>(minbuf, out, 1.0f / BATCH);
    }
}